// Round 5
// baseline (351.178 us; speedup 1.0000x reference)
//
#include <hip/hip_runtime.h>
#include <cmath>

#define TPB 256
#define NSLOPE 0.2f
#define SEPS 1e-16f

#define BSH 8                 // nodes per bucket = 256
#define BSZ 256
#define NBMAX 1024            // supports N up to 262144
#define NCHUNK 256            // blocks for bucket hist/scatter

__device__ __forceinline__ float lrelu(float v) { return v > 0.f ? v : NSLOPE * v; }
__device__ __forceinline__ float elu1(float v)  { return v > 0.f ? v : expm1f(v); }

// ---- layer-1 scalar prep: SD[0..3]=S1[h]=sum_c W1[h,c]*att_src1[h,c]; SD[4..7]=D1 ----
__global__ void k_prep1(const float* __restrict__ W1, const float* __restrict__ as1,
                        const float* __restrict__ ad1, float* __restrict__ SD) {
    int t = threadIdx.x;
    if (t < 8) {
        int h = t & 3;
        const float* att = (t >= 4) ? ad1 : as1;
        float acc = 0.f;
        #pragma unroll
        for (int c = 0; c < 8; ++c) acc += W1[h*8+c] * att[h*8+c];
        SD[t] = acc;
    }
}

// ---- pass A: coarse bucket histogram (LDS, then ~NB global atomics per block) ----
__global__ void k_bhist(const int* __restrict__ dstI, int E, int N, int NB, int chunk,
                        int* __restrict__ bucketCnt) {
    __shared__ int cnt[NBMAX];
    for (int i = threadIdx.x; i < NB; i += blockDim.x) cnt[i] = 0;
    __syncthreads();
    int ET = E + N;
    int beg = blockIdx.x * chunk;
    int end = min(beg + chunk, ET);
    for (int e = beg + threadIdx.x; e < end; e += blockDim.x) {
        int d = (e < E) ? dstI[e] : (e - E);
        atomicAdd(&cnt[d >> BSH], 1);
    }
    __syncthreads();
    for (int i = threadIdx.x; i < NB; i += blockDim.x)
        if (cnt[i]) atomicAdd(&bucketCnt[i], cnt[i]);
}

// ---- pass B: one-block exclusive scan of bucket counts ----
__global__ void k_bscan(const int* __restrict__ bucketCnt, int* __restrict__ bucketBase,
                        int* __restrict__ bucketCursor, int NB, int ET,
                        int* __restrict__ offsets, int N) {
    __shared__ int tmp[NBMAX];
    int t = threadIdx.x;
    int v = (t < NB) ? bucketCnt[t] : 0;
    tmp[t] = v;
    __syncthreads();
    for (int off = 1; off < NBMAX; off <<= 1) {
        int u = (t >= off) ? tmp[t - off] : 0;
        __syncthreads();
        tmp[t] += u;
        __syncthreads();
    }
    if (t < NB) { int ex = tmp[t] - v; bucketBase[t] = ex; bucketCursor[t] = ex; }
    if (t == 0) { bucketBase[NB] = ET; offsets[N] = ET; }
}

// ---- pass C: bucket scatter of packed (src<<8|dstLow); one claim-atomic per (block,bucket) ----
__global__ void k_bscatter(const int* __restrict__ srcI, const int* __restrict__ dstI,
                           int E, int N, int NB, int chunk,
                           int* __restrict__ bucketCursor, int* __restrict__ pk) {
    __shared__ int cnt[NBMAX];
    __shared__ int base[NBMAX];
    for (int i = threadIdx.x; i < NB; i += blockDim.x) cnt[i] = 0;
    __syncthreads();
    int ET = E + N;
    int beg = blockIdx.x * chunk;
    int end = min(beg + chunk, ET);
    for (int e = beg + threadIdx.x; e < end; e += blockDim.x) {
        int d = (e < E) ? dstI[e] : (e - E);
        atomicAdd(&cnt[d >> BSH], 1);
    }
    __syncthreads();
    for (int i = threadIdx.x; i < NB; i += blockDim.x) {
        base[i] = cnt[i] ? atomicAdd(&bucketCursor[i], cnt[i]) : 0;
        cnt[i] = 0;
    }
    __syncthreads();
    for (int e = beg + threadIdx.x; e < end; e += blockDim.x) {
        int s, d;
        if (e < E) { s = srcI[e]; d = dstI[e]; } else { s = d = e - E; }
        int b = d >> BSH;
        int r = atomicAdd(&cnt[b], 1);
        pk[base[b] + r] = (s << BSH) | (d & (BSZ - 1));
    }
}

// ---- pass D: per-bucket fine sort; emits offsets[], sortedSrc, sortedDst ----
__global__ void k_bsort(const int* __restrict__ pk, const int* __restrict__ bucketBase,
                        int N, int* __restrict__ offsets,
                        int* __restrict__ sortedSrc, int* __restrict__ sortedDst) {
    __shared__ int cnt[BSZ];
    __shared__ int offl[BSZ];
    int b = blockIdx.x;
    int rbeg = bucketBase[b], rend = bucketBase[b + 1];
    int t = threadIdx.x;                    // 256 threads
    cnt[t] = 0;
    __syncthreads();
    for (int i = rbeg + t; i < rend; i += BSZ)
        atomicAdd(&cnt[pk[i] & (BSZ - 1)], 1);
    __syncthreads();
    int v = cnt[t];
    offl[t] = v;
    __syncthreads();
    for (int off = 1; off < BSZ; off <<= 1) {
        int u = (t >= off) ? offl[t - off] : 0;
        __syncthreads();
        offl[t] += u;
        __syncthreads();
    }
    int ex = offl[t] - v;                   // exclusive prefix within bucket
    int d = (b << BSH) + t;
    if (d < N) offsets[d] = rbeg + ex;
    cnt[t] = 0;                             // reuse as per-node cursor
    offl[t] = ex;
    __syncthreads();
    for (int i = rbeg + t; i < rend; i += BSZ) {
        int p = pk[i];
        int dl = p & (BSZ - 1);
        int r = atomicAdd(&cnt[dl], 1);
        int pos = rbeg + offl[dl] + r;
        sortedSrc[pos] = p >> BSH;
        sortedDst[pos] = (b << BSH) | dl;
    }
}

// ---- layer 1 fused: single-pass gather softmax (H=4) -> bias -> ELU ----
// h1[s,h,c] = x[s]*W1[h,c]  =>  sum_e alpha*h1[s] = (sum_e alpha*x[s]) * W1[h,:]
__global__ void k_layer1(const int* __restrict__ offsets, const int* __restrict__ sortedSrc,
                         const float* __restrict__ x, const float* __restrict__ SD,
                         const float* __restrict__ W1, const float* __restrict__ b1,
                         float* __restrict__ out1p, int N) {
    int d = blockIdx.x * blockDim.x + threadIdx.x;
    if (d >= N) return;
    int beg = offsets[d], end = offsets[d+1];
    float xd = x[d];
    float S0 = SD[0], S1 = SD[1], S2 = SD[2], S3 = SD[3];
    float D0 = xd*SD[4], D1 = xd*SD[5], D2 = xd*SD[6], D3 = xd*SD[7];
    float s0 = 0.f, s1 = 0.f, s2 = 0.f, s3 = 0.f;
    float g0 = 0.f, g1 = 0.f, g2 = 0.f, g3 = 0.f;
    for (int i = beg; i < end; ++i) {
        float xs = x[sortedSrc[i]];
        float p;
        p = __expf(lrelu(xs*S0 + D0)); s0 += p; g0 += p * xs;
        p = __expf(lrelu(xs*S1 + D1)); s1 += p; g1 += p * xs;
        p = __expf(lrelu(xs*S2 + D2)); s2 += p; g2 += p * xs;
        p = __expf(lrelu(xs*S3 + D3)); s3 += p; g3 += p * xs;
    }
    float g[4];
    g[0] = g0 / (s0 + SEPS); g[1] = g1 / (s1 + SEPS);
    g[2] = g2 / (s2 + SEPS); g[3] = g3 / (s3 + SEPS);
    float* orow = out1p + (size_t)d * 32;
    #pragma unroll
    for (int h = 0; h < 4; ++h)
        #pragma unroll
        for (int c = 0; c < 8; ++c)
            orow[h*8+c] = elu1(g[h] * W1[h*8+c] + b1[h*8+c]);
}

// ---- h2[n,j] = sum_k out1p[n,k]*W2[k,j] fused with att coeffs (waves node-aligned) ----
__global__ void k_h2att(const float* __restrict__ h1p, const float* __restrict__ W2,
                        const float* __restrict__ attS, const float* __restrict__ attD,
                        float* __restrict__ h2, float* __restrict__ aS, float* __restrict__ aD,
                        int N) {
    int i = blockIdx.x * blockDim.x + threadIdx.x;
    if (i >= N * 64) return;
    int n = i >> 6, j = i & 63;
    const float* row = h1p + (size_t)n * 32;
    float acc = 0.f;
    #pragma unroll
    for (int k = 0; k < 32; ++k) acc += row[k] * W2[k*64 + j];
    h2[i] = acc;
    float ps = acc * attS[j];
    float pd = acc * attD[j];
    #pragma unroll
    for (int m = 1; m < 8; m <<= 1) {
        ps += __shfl_xor(ps, m);
        pd += __shfl_xor(pd, m);
    }
    int h = j >> 3, c = j & 7;
    if (c == 0) aS[(size_t)n*8 + h] = ps;
    if (c == 1) aD[(size_t)n*8 + h] = pd;
}

// ---- layer 2 scores: one thread per (edge,head); 64 distinct exps per wave-instr ----
__global__ void k_score(const int* __restrict__ ss, const int* __restrict__ sd,
                        const float* __restrict__ aS, const float* __restrict__ aD,
                        float* __restrict__ pbuf, int ET8) {
    int i = blockIdx.x * blockDim.x + threadIdx.x;
    if (i >= ET8) return;
    int e = i >> 3, h = i & 7;
    int s = ss[e], d = sd[e];
    float v = aS[(size_t)s*8 + h] + aD[(size_t)d*8 + h];
    pbuf[i] = __expf(lrelu(v));
}

// ---- layer 2 aggregation: wave-per-node; per edge = 2 loads + fma + add ----
__global__ void k_agg(const int* __restrict__ offsets, const int* __restrict__ ss,
                      const float* __restrict__ pbuf, const float* __restrict__ h2,
                      const float* __restrict__ b2, const float* __restrict__ fcw,
                      const float* __restrict__ fcb, float* __restrict__ out, int N) {
    int lane = threadIdx.x & 63;
    int d = blockIdx.x * 4 + (threadIdx.x >> 6);
    if (d >= N) return;
    int h = lane >> 3;
    int beg = offsets[d], end = offsets[d+1];
    float sum = 0.f, acc = 0.f;
    int e = beg;
    for (; e + 4 <= end; e += 4) {
        int s0 = ss[e], s1 = ss[e+1], s2 = ss[e+2], s3 = ss[e+3];
        float p0 = pbuf[(size_t)e*8 + h],     p1 = pbuf[(size_t)(e+1)*8 + h];
        float p2 = pbuf[(size_t)(e+2)*8 + h], p3 = pbuf[(size_t)(e+3)*8 + h];
        float g0 = h2[(size_t)s0*64 + lane], g1 = h2[(size_t)s1*64 + lane];
        float g2 = h2[(size_t)s2*64 + lane], g3 = h2[(size_t)s3*64 + lane];
        acc += p0*g0 + p1*g1 + p2*g2 + p3*g3;
        sum += (p0 + p1) + (p2 + p3);
    }
    for (; e < end; ++e) {
        int s = ss[e];
        float p = pbuf[(size_t)e*8 + h];
        sum += p;
        acc += p * h2[(size_t)s*64 + lane];
    }
    float r = acc / (sum + SEPS);
    float t = elu1(r + b2[lane]) * fcw[lane];
    #pragma unroll
    for (int m = 32; m; m >>= 1) t += __shfl_xor(t, m);
    if (lane == 0) out[d] = t + fcb[0];
}

extern "C" void kernel_launch(void* const* d_in, const int* in_sizes, int n_in,
                              void* d_out, int out_size, void* d_ws, size_t ws_size,
                              hipStream_t stream) {
    const float* x    = (const float*)d_in[0];
    const int*   ei   = (const int*)  d_in[1];
    const float* W1   = (const float*)d_in[2];
    const float* as1  = (const float*)d_in[3];
    const float* ad1  = (const float*)d_in[4];
    const float* b1   = (const float*)d_in[5];
    const float* W2   = (const float*)d_in[6];
    const float* attS2= (const float*)d_in[7];
    const float* attD2= (const float*)d_in[8];
    const float* b2   = (const float*)d_in[9];
    const float* fcw  = (const float*)d_in[10];
    const float* fcb  = (const float*)d_in[11];
    float* out = (float*)d_out;

    int N = in_sizes[0];          // x is [N,1]
    int E = in_sizes[1] / 2;      // edge_index is [2,E]
    int ET = E + N;               // with self-loops
    int NB = (N + BSZ - 1) / BSZ; // coarse buckets (<= NBMAX)

    const int* srcI = ei;
    const int* dstI = ei + E;

    float* ws = (float*)d_ws;
    size_t off = 0;
    float* SD           = ws + off; off += 16;
    int*   bucketCnt    = (int*)(ws + off); off += NBMAX;
    int*   bucketBase   = (int*)(ws + off); off += NBMAX + 16;
    int*   bucketCursor = (int*)(ws + off); off += NBMAX;
    int*   offsets      = (int*)(ws + off); off += (size_t)N + 16;
    int*   pk           = (int*)(ws + off); off += (size_t)ET;
    int*   sortedSrc    = (int*)(ws + off); off += (size_t)ET;
    int*   sortedDst    = (int*)(ws + off); off += (size_t)ET;
    float* pbuf         = ws + off; off += (size_t)ET * 8;
    float* aS2          = ws + off; off += (size_t)N * 8;
    float* aD2          = ws + off; off += (size_t)N * 8;
    float* h2           = ws + off; off += (size_t)N * 64;
    float* out1p        = ws + off; off += (size_t)N * 32;

    hipMemsetAsync(bucketCnt, 0, NBMAX * sizeof(int), stream);

    k_prep1<<<1, 64, 0, stream>>>(W1, as1, ad1, SD);

    int chunk = (ET + NCHUNK - 1) / NCHUNK;
    k_bhist   <<<NCHUNK, TPB, 0, stream>>>(dstI, E, N, NB, chunk, bucketCnt);
    k_bscan   <<<1, NBMAX, 0, stream>>>(bucketCnt, bucketBase, bucketCursor, NB, ET, offsets, N);
    k_bscatter<<<NCHUNK, TPB, 0, stream>>>(srcI, dstI, E, N, NB, chunk, bucketCursor, pk);
    k_bsort   <<<NB, BSZ, 0, stream>>>(pk, bucketBase, N, offsets, sortedSrc, sortedDst);

    int gN = (N + TPB - 1) / TPB;
    k_layer1 <<<gN, TPB, 0, stream>>>(offsets, sortedSrc, x, SD, W1, b1, out1p, N);
    k_h2att  <<<(N*64 + TPB - 1) / TPB, TPB, 0, stream>>>(out1p, W2, attS2, attD2, h2, aS2, aD2, N);
    k_score  <<<((size_t)ET*8 + TPB - 1) / TPB, TPB, 0, stream>>>(sortedSrc, sortedDst, aS2, aD2, pbuf, ET*8);
    k_agg    <<<(N + 3) / 4, TPB, 0, stream>>>(offsets, sortedSrc, pbuf, h2, b2, fcw, fcb, out, N);
}

// Round 6
// 330.793 us; speedup vs baseline: 1.0616x; 1.0616x over previous
//
#include <hip/hip_runtime.h>
#include <cmath>

#define TPB 256
#define NSLOPE 0.2f
#define SEPS 1e-16f

#define BSH 8                 // nodes per bucket = 256
#define BSZ 256
#define NBMAX 1024            // supports N up to 262144
#define NCHUNK 256            // blocks for bucket hist/scatter

__device__ __forceinline__ float lrelu(float v) { return v > 0.f ? v : NSLOPE * v; }
__device__ __forceinline__ float elu1(float v)  { return v > 0.f ? v : expm1f(v); }

// ---- layer-1 scalar prep: SD[0..3]=S1[h]=sum_c W1[h,c]*att_src1[h,c]; SD[4..7]=D1 ----
__global__ void k_prep1(const float* __restrict__ W1, const float* __restrict__ as1,
                        const float* __restrict__ ad1, float* __restrict__ SD) {
    int t = threadIdx.x;
    if (t < 8) {
        int h = t & 3;
        const float* att = (t >= 4) ? ad1 : as1;
        float acc = 0.f;
        #pragma unroll
        for (int c = 0; c < 8; ++c) acc += W1[h*8+c] * att[h*8+c];
        SD[t] = acc;
    }
}

// ---- pass A: coarse bucket histogram (LDS, then ~NB global atomics per block) ----
__global__ void k_bhist(const int* __restrict__ dstI, int E, int N, int NB, int chunk,
                        int* __restrict__ bucketCnt) {
    __shared__ int cnt[NBMAX];
    for (int i = threadIdx.x; i < NB; i += blockDim.x) cnt[i] = 0;
    __syncthreads();
    int ET = E + N;
    int beg = blockIdx.x * chunk;
    int end = min(beg + chunk, ET);
    for (int e = beg + threadIdx.x; e < end; e += blockDim.x) {
        int d = (e < E) ? dstI[e] : (e - E);
        atomicAdd(&cnt[d >> BSH], 1);
    }
    __syncthreads();
    for (int i = threadIdx.x; i < NB; i += blockDim.x)
        if (cnt[i]) atomicAdd(&bucketCnt[i], cnt[i]);
}

// ---- pass B: one-block exclusive scan of bucket counts ----
__global__ void k_bscan(const int* __restrict__ bucketCnt, int* __restrict__ bucketBase,
                        int* __restrict__ bucketCursor, int NB, int ET,
                        int* __restrict__ offsets, int N) {
    __shared__ int tmp[NBMAX];
    int t = threadIdx.x;
    int v = (t < NB) ? bucketCnt[t] : 0;
    tmp[t] = v;
    __syncthreads();
    for (int off = 1; off < NBMAX; off <<= 1) {
        int u = (t >= off) ? tmp[t - off] : 0;
        __syncthreads();
        tmp[t] += u;
        __syncthreads();
    }
    if (t < NB) { int ex = tmp[t] - v; bucketBase[t] = ex; bucketCursor[t] = ex; }
    if (t == 0) { bucketBase[NB] = ET; offsets[N] = ET; }
}

// ---- pass C: bucket scatter of packed (src<<8|dstLow); one claim-atomic per (block,bucket) ----
__global__ void k_bscatter(const int* __restrict__ srcI, const int* __restrict__ dstI,
                           int E, int N, int NB, int chunk,
                           int* __restrict__ bucketCursor, int* __restrict__ pk) {
    __shared__ int cnt[NBMAX];
    __shared__ int base[NBMAX];
    for (int i = threadIdx.x; i < NB; i += blockDim.x) cnt[i] = 0;
    __syncthreads();
    int ET = E + N;
    int beg = blockIdx.x * chunk;
    int end = min(beg + chunk, ET);
    for (int e = beg + threadIdx.x; e < end; e += blockDim.x) {
        int d = (e < E) ? dstI[e] : (e - E);
        atomicAdd(&cnt[d >> BSH], 1);
    }
    __syncthreads();
    for (int i = threadIdx.x; i < NB; i += blockDim.x) {
        base[i] = cnt[i] ? atomicAdd(&bucketCursor[i], cnt[i]) : 0;
        cnt[i] = 0;
    }
    __syncthreads();
    for (int e = beg + threadIdx.x; e < end; e += blockDim.x) {
        int s, d;
        if (e < E) { s = srcI[e]; d = dstI[e]; } else { s = d = e - E; }
        int b = d >> BSH;
        int r = atomicAdd(&cnt[b], 1);
        pk[base[b] + r] = (s << BSH) | (d & (BSZ - 1));
    }
}

// ---- mega: per-bucket fine sort + layer-1 softmax + h2/att, all in one block ----
__global__ void k_mega(const int* __restrict__ pk, const int* __restrict__ bucketBase,
                       const float* __restrict__ x, const float* __restrict__ SD,
                       const float* __restrict__ W1, const float* __restrict__ b1,
                       const float* __restrict__ W2, const float* __restrict__ attS,
                       const float* __restrict__ attD, int N,
                       int* __restrict__ offsets, int* __restrict__ sortedSrc,
                       float* __restrict__ h2, float* __restrict__ aS, float* __restrict__ aD) {
    __shared__ int cnt[BSZ];
    __shared__ int offl[BSZ];
    __shared__ float lds1[BSZ][33];       // +1 pad: conflict-free row writes
    __shared__ float ldsW2[32 * 64];
    int b = blockIdx.x;
    int t = threadIdx.x;
    int rbeg = bucketBase[b], rend = bucketBase[b + 1];
    for (int i = t; i < 2048; i += BSZ) ldsW2[i] = W2[i];
    cnt[t] = 0;
    __syncthreads();
    // phase 1a: fine histogram
    for (int i = rbeg + t; i < rend; i += BSZ)
        atomicAdd(&cnt[pk[i] & (BSZ - 1)], 1);
    __syncthreads();
    int v = cnt[t];
    offl[t] = v;
    __syncthreads();
    for (int off = 1; off < BSZ; off <<= 1) {
        int u = (t >= off) ? offl[t - off] : 0;
        __syncthreads();
        offl[t] += u;
        __syncthreads();
    }
    int ex = offl[t] - v;                 // exclusive prefix within bucket
    int myBeg = rbeg + ex, myEnd = myBeg + v;
    int d = (b << BSH) + t;
    if (d < N) offsets[d] = myBeg;
    cnt[t] = 0;                           // reuse as per-node cursor
    offl[t] = ex;
    __syncthreads();
    // phase 1b: scatter src into bucket-local sorted order
    for (int i = rbeg + t; i < rend; i += BSZ) {
        int p = pk[i];
        int dl = p & (BSZ - 1);
        int r = atomicAdd(&cnt[dl], 1);
        sortedSrc[rbeg + offl[dl] + r] = p >> BSH;
    }
    __syncthreads();                      // drains vmcnt: sortedSrc visible block-wide
    // phase 2: layer-1 softmax for node d (thread-per-node)
    if (d < N) {
        float xd = x[d];
        float S0 = SD[0], S1 = SD[1], S2 = SD[2], S3 = SD[3];
        float D0 = xd*SD[4], D1 = xd*SD[5], D2 = xd*SD[6], D3 = xd*SD[7];
        float s0 = 0.f, s1 = 0.f, s2 = 0.f, s3 = 0.f;
        float g0 = 0.f, g1 = 0.f, g2 = 0.f, g3 = 0.f;
        for (int i = myBeg; i < myEnd; ++i) {
            float xs = x[sortedSrc[i]];
            float p;
            p = __expf(lrelu(xs*S0 + D0)); s0 += p; g0 += p * xs;
            p = __expf(lrelu(xs*S1 + D1)); s1 += p; g1 += p * xs;
            p = __expf(lrelu(xs*S2 + D2)); s2 += p; g2 += p * xs;
            p = __expf(lrelu(xs*S3 + D3)); s3 += p; g3 += p * xs;
        }
        float gg[4];
        gg[0] = g0 / (s0 + SEPS); gg[1] = g1 / (s1 + SEPS);
        gg[2] = g2 / (s2 + SEPS); gg[3] = g3 / (s3 + SEPS);
        #pragma unroll
        for (int hh = 0; hh < 4; ++hh)
            #pragma unroll
            for (int cc = 0; cc < 8; ++cc)
                lds1[t][hh*8+cc] = elu1(gg[hh] * W1[hh*8+cc] + b1[hh*8+cc]);
    }
    __syncthreads();
    // phase 3: h2 = lds1 @ W2 (+ att coeffs); one node per wave per round
    int lane = t & 63;                    // channel j
    int sub = t >> 6;                     // wave id 0..3
    int nCnt = min(BSZ, N - (b << BSH));
    for (int nn = sub; nn < nCnt; nn += 4) {
        const float* row = lds1[nn];
        float acc = 0.f;
        #pragma unroll
        for (int k = 0; k < 32; ++k) acc += row[k] * ldsW2[k*64 + lane];
        int node = (b << BSH) + nn;
        h2[(size_t)node*64 + lane] = acc;
        float ps = acc * attS[lane];
        float pd = acc * attD[lane];
        #pragma unroll
        for (int m = 1; m < 8; m <<= 1) {
            ps += __shfl_xor(ps, m);
            pd += __shfl_xor(pd, m);
        }
        int hh = lane >> 3, cc = lane & 7;
        if (cc == 0) aS[(size_t)node*8 + hh] = ps;
        if (cc == 1) aD[(size_t)node*8 + hh] = pd;
    }
}

// ---- layer 2: wave-per-node; scores computed cooperatively (64 distinct exps/wave-instr),
//      broadcast via shuffle; per edge = 1 h2 row load + fma + add ----
__global__ void k_agg(const int* __restrict__ offsets, const int* __restrict__ ss,
                      const float* __restrict__ aS, const float* __restrict__ aD,
                      const float* __restrict__ h2, const float* __restrict__ b2,
                      const float* __restrict__ fcw, const float* __restrict__ fcb,
                      float* __restrict__ out, int N) {
    int lane = threadIdx.x & 63;
    int d = blockIdx.x * 4 + (threadIdx.x >> 6);
    if (d >= N) return;
    int h = lane >> 3, c8 = lane & 7;
    int gbase = lane & 56;
    int beg = offsets[d], end = offsets[d+1];
    float adh = aD[(size_t)d*8 + h];
    float sum = 0.f, acc = 0.f;
    for (int e0 = beg; e0 < end; e0 += 8) {
        int idx = e0 + c8;
        int sv = (idx < end) ? ss[idx] : 0;
        float p = (idx < end) ? __expf(lrelu(aS[(size_t)sv*8 + h] + adh)) : 0.f;
        int kmax = end - e0; if (kmax > 8) kmax = 8;
        #pragma unroll 8
        for (int k = 0; k < kmax; ++k) {
            float pk_ = __shfl(p, gbase + k);
            int   sk  = __shfl(sv, gbase + k);
            float g = h2[(size_t)sk*64 + lane];
            acc += pk_ * g;
            sum += pk_;
        }
    }
    float r = acc / (sum + SEPS);
    float tt = elu1(r + b2[lane]) * fcw[lane];
    #pragma unroll
    for (int m = 32; m; m >>= 1) tt += __shfl_xor(tt, m);
    if (lane == 0) out[d] = tt + fcb[0];
}

extern "C" void kernel_launch(void* const* d_in, const int* in_sizes, int n_in,
                              void* d_out, int out_size, void* d_ws, size_t ws_size,
                              hipStream_t stream) {
    const float* x    = (const float*)d_in[0];
    const int*   ei   = (const int*)  d_in[1];
    const float* W1   = (const float*)d_in[2];
    const float* as1  = (const float*)d_in[3];
    const float* ad1  = (const float*)d_in[4];
    const float* b1   = (const float*)d_in[5];
    const float* W2   = (const float*)d_in[6];
    const float* attS2= (const float*)d_in[7];
    const float* attD2= (const float*)d_in[8];
    const float* b2   = (const float*)d_in[9];
    const float* fcw  = (const float*)d_in[10];
    const float* fcb  = (const float*)d_in[11];
    float* out = (float*)d_out;

    int N = in_sizes[0];          // x is [N,1]
    int E = in_sizes[1] / 2;      // edge_index is [2,E]
    int ET = E + N;               // with self-loops
    int NB = (N + BSZ - 1) / BSZ; // coarse buckets (<= NBMAX)

    const int* srcI = ei;
    const int* dstI = ei + E;

    float* ws = (float*)d_ws;
    size_t off = 0;
    float* SD           = ws + off; off += 16;
    int*   bucketCnt    = (int*)(ws + off); off += NBMAX;
    int*   bucketBase   = (int*)(ws + off); off += NBMAX + 16;
    int*   bucketCursor = (int*)(ws + off); off += NBMAX;
    int*   offsets      = (int*)(ws + off); off += (size_t)N + 16;
    int*   pk           = (int*)(ws + off); off += (size_t)ET;
    int*   sortedSrc    = (int*)(ws + off); off += (size_t)ET;
    float* aS2          = ws + off; off += (size_t)N * 8;
    float* aD2          = ws + off; off += (size_t)N * 8;
    float* h2           = ws + off; off += (size_t)N * 64;

    hipMemsetAsync(bucketCnt, 0, NBMAX * sizeof(int), stream);

    k_prep1<<<1, 64, 0, stream>>>(W1, as1, ad1, SD);

    int chunk = (ET + NCHUNK - 1) / NCHUNK;
    k_bhist   <<<NCHUNK, TPB, 0, stream>>>(dstI, E, N, NB, chunk, bucketCnt);
    k_bscan   <<<1, NBMAX, 0, stream>>>(bucketCnt, bucketBase, bucketCursor, NB, ET, offsets, N);
    k_bscatter<<<NCHUNK, TPB, 0, stream>>>(srcI, dstI, E, N, NB, chunk, bucketCursor, pk);
    k_mega    <<<NB, BSZ, 0, stream>>>(pk, bucketBase, x, SD, W1, b1, W2, attS2, attD2,
                                       N, offsets, sortedSrc, h2, aS2, aD2);
    k_agg     <<<(N + 3) / 4, TPB, 0, stream>>>(offsets, sortedSrc, aS2, aD2, h2,
                                                b2, fcw, fcb, out, N);
}

// Round 7
// 286.221 us; speedup vs baseline: 1.2269x; 1.1557x over previous
//
#include <hip/hip_runtime.h>
#include <cmath>

#define TPB 256
#define NSLOPE 0.2f
#define SEPS 1e-16f

#define BSH 8                 // nodes per bucket = 256
#define BSZ 256
#define NBMAX 1024            // supports N up to 262144
#define NCHUNK 256            // blocks for bucket hist/scatter
#define MAXDEG 96             // per-wave LDS score staging cap (P[deg>96] ~ 0 for Poisson(17))

__device__ __forceinline__ float lrelu(float v) { return v > 0.f ? v : NSLOPE * v; }
__device__ __forceinline__ float elu1(float v)  { return v > 0.f ? v : expm1f(v); }

// ---- layer-1 scalar prep: SD[0..3]=S1[h]=sum_c W1[h,c]*att_src1[h,c]; SD[4..7]=D1 ----
__global__ void k_prep1(const float* __restrict__ W1, const float* __restrict__ as1,
                        const float* __restrict__ ad1, float* __restrict__ SD) {
    int t = threadIdx.x;
    if (t < 8) {
        int h = t & 3;
        const float* att = (t >= 4) ? ad1 : as1;
        float acc = 0.f;
        #pragma unroll
        for (int c = 0; c < 8; ++c) acc += W1[h*8+c] * att[h*8+c];
        SD[t] = acc;
    }
}

// ---- pass A: coarse bucket histogram; persists per-(block,bucket) counts ----
__global__ void k_bhist(const int* __restrict__ dstI, int E, int N, int NB, int chunk,
                        int* __restrict__ bucketCnt, int* __restrict__ blkCnt) {
    __shared__ int cnt[NBMAX];
    for (int i = threadIdx.x; i < NB; i += blockDim.x) cnt[i] = 0;
    __syncthreads();
    int ET = E + N;
    int beg = blockIdx.x * chunk;
    int end = min(beg + chunk, ET);
    for (int e = beg + threadIdx.x; e < end; e += blockDim.x) {
        int d = (e < E) ? dstI[e] : (e - E);
        atomicAdd(&cnt[d >> BSH], 1);
    }
    __syncthreads();
    int* myBlk = blkCnt + (size_t)blockIdx.x * NBMAX;
    for (int i = threadIdx.x; i < NB; i += blockDim.x) {
        int c = cnt[i];
        myBlk[i] = c;
        if (c) atomicAdd(&bucketCnt[i], c);
    }
}

// ---- pass B: one-block exclusive scan of bucket counts ----
__global__ void k_bscan(const int* __restrict__ bucketCnt, int* __restrict__ bucketBase,
                        int* __restrict__ bucketCursor, int NB, int ET,
                        int* __restrict__ offsets, int N) {
    __shared__ int tmp[NBMAX];
    int t = threadIdx.x;
    int v = (t < NB) ? bucketCnt[t] : 0;
    tmp[t] = v;
    __syncthreads();
    for (int off = 1; off < NBMAX; off <<= 1) {
        int u = (t >= off) ? tmp[t - off] : 0;
        __syncthreads();
        tmp[t] += u;
        __syncthreads();
    }
    if (t < NB) { int ex = tmp[t] - v; bucketBase[t] = ex; bucketCursor[t] = ex; }
    if (t == 0) { bucketBase[NB] = ET; offsets[N] = ET; }
}

// ---- pass C: bucket scatter of packed (src<<8|dstLow); counts pre-read from blkCnt ----
__global__ void k_bscatter(const int* __restrict__ srcI, const int* __restrict__ dstI,
                           int E, int N, int NB, int chunk,
                           const int* __restrict__ blkCnt,
                           int* __restrict__ bucketCursor, int* __restrict__ pk) {
    __shared__ int cnt[NBMAX];
    __shared__ int base[NBMAX];
    const int* myBlk = blkCnt + (size_t)blockIdx.x * NBMAX;
    for (int i = threadIdx.x; i < NB; i += blockDim.x) {
        int c = myBlk[i];
        base[i] = c ? atomicAdd(&bucketCursor[i], c) : 0;
        cnt[i] = 0;
    }
    __syncthreads();
    int ET = E + N;
    int beg = blockIdx.x * chunk;
    int end = min(beg + chunk, ET);
    for (int e = beg + threadIdx.x; e < end; e += blockDim.x) {
        int s, d;
        if (e < E) { s = srcI[e]; d = dstI[e]; } else { s = d = e - E; }
        int b = d >> BSH;
        int r = atomicAdd(&cnt[b], 1);
        pk[base[b] + r] = (s << BSH) | (d & (BSZ - 1));
    }
}

// ---- mega: per-bucket fine sort + layer-1 softmax + h2/att, all in one block ----
__global__ void k_mega(const int* __restrict__ pk, const int* __restrict__ bucketBase,
                       const float* __restrict__ x, const float* __restrict__ SD,
                       const float* __restrict__ W1, const float* __restrict__ b1,
                       const float* __restrict__ W2, const float* __restrict__ attS,
                       const float* __restrict__ attD, int N,
                       int* __restrict__ offsets, int* __restrict__ sortedSrc,
                       float* __restrict__ h2, float* __restrict__ aS, float* __restrict__ aD) {
    __shared__ int cnt[BSZ];
    __shared__ int offl[BSZ];
    __shared__ float lds1[BSZ][33];       // +1 pad: conflict-free row writes
    __shared__ float ldsW2[32 * 64];
    int b = blockIdx.x;
    int t = threadIdx.x;
    int rbeg = bucketBase[b], rend = bucketBase[b + 1];
    for (int i = t; i < 2048; i += BSZ) ldsW2[i] = W2[i];
    cnt[t] = 0;
    __syncthreads();
    // phase 1a: fine histogram
    for (int i = rbeg + t; i < rend; i += BSZ)
        atomicAdd(&cnt[pk[i] & (BSZ - 1)], 1);
    __syncthreads();
    int v = cnt[t];
    offl[t] = v;
    __syncthreads();
    for (int off = 1; off < BSZ; off <<= 1) {
        int u = (t >= off) ? offl[t - off] : 0;
        __syncthreads();
        offl[t] += u;
        __syncthreads();
    }
    int ex = offl[t] - v;                 // exclusive prefix within bucket
    int myBeg = rbeg + ex, myEnd = myBeg + v;
    int d = (b << BSH) + t;
    if (d < N) offsets[d] = myBeg;
    cnt[t] = 0;                           // reuse as per-node cursor
    offl[t] = ex;
    __syncthreads();
    // phase 1b: scatter src into bucket-local sorted order
    for (int i = rbeg + t; i < rend; i += BSZ) {
        int p = pk[i];
        int dl = p & (BSZ - 1);
        int r = atomicAdd(&cnt[dl], 1);
        sortedSrc[rbeg + offl[dl] + r] = p >> BSH;
    }
    __syncthreads();
    // phase 2: layer-1 softmax for node d (thread-per-node)
    if (d < N) {
        float xd = x[d];
        float S0 = SD[0], S1 = SD[1], S2 = SD[2], S3 = SD[3];
        float D0 = xd*SD[4], D1 = xd*SD[5], D2 = xd*SD[6], D3 = xd*SD[7];
        float s0 = 0.f, s1 = 0.f, s2 = 0.f, s3 = 0.f;
        float g0 = 0.f, g1 = 0.f, g2 = 0.f, g3 = 0.f;
        for (int i = myBeg; i < myEnd; ++i) {
            float xs = x[sortedSrc[i]];
            float p;
            p = __expf(lrelu(xs*S0 + D0)); s0 += p; g0 += p * xs;
            p = __expf(lrelu(xs*S1 + D1)); s1 += p; g1 += p * xs;
            p = __expf(lrelu(xs*S2 + D2)); s2 += p; g2 += p * xs;
            p = __expf(lrelu(xs*S3 + D3)); s3 += p; g3 += p * xs;
        }
        float gg[4];
        gg[0] = g0 / (s0 + SEPS); gg[1] = g1 / (s1 + SEPS);
        gg[2] = g2 / (s2 + SEPS); gg[3] = g3 / (s3 + SEPS);
        #pragma unroll
        for (int hh = 0; hh < 4; ++hh)
            #pragma unroll
            for (int cc = 0; cc < 8; ++cc)
                lds1[t][hh*8+cc] = elu1(gg[hh] * W1[hh*8+cc] + b1[hh*8+cc]);
    }
    __syncthreads();
    // phase 3: h2 = lds1 @ W2 (+ att coeffs); one node per wave per round
    int lane = t & 63;                    // channel j
    int sub = t >> 6;                     // wave id 0..3
    int nCnt = min(BSZ, N - (b << BSH));
    float attSl = attS[lane], attDl = attD[lane];
    for (int nn = sub; nn < nCnt; nn += 4) {
        const float* row = lds1[nn];
        float acc = 0.f;
        #pragma unroll
        for (int k = 0; k < 32; ++k) acc += row[k] * ldsW2[k*64 + lane];
        int node = (b << BSH) + nn;
        h2[(size_t)node*64 + lane] = acc;
        float ps = acc * attSl;
        float pd = acc * attDl;
        #pragma unroll
        for (int m = 1; m < 8; m <<= 1) {
            ps += __shfl_xor(ps, m);
            pd += __shfl_xor(pd, m);
        }
        int hh = lane >> 3, cc = lane & 7;
        if (cc == 0) aS[(size_t)node*8 + hh] = ps;
        if (cc == 1) aD[(size_t)node*8 + hh] = pd;
    }
}

// ---- layer 2: wave-per-node; scores precomputed into LDS by the wave itself
//      (64 distinct exps per wave-instr), then round-5-style unrolled gather ----
__global__ void k_agg(const int* __restrict__ offsets, const int* __restrict__ ss,
                      const float* __restrict__ aS, const float* __restrict__ aD,
                      const float* __restrict__ h2, const float* __restrict__ b2,
                      const float* __restrict__ fcw, const float* __restrict__ fcb,
                      float* __restrict__ out, int N) {
    __shared__ float pl[4][MAXDEG * 8];
    __shared__ int   sl[4][MAXDEG];
    int lane = threadIdx.x & 63;
    int w = threadIdx.x >> 6;
    int d = blockIdx.x * 4 + w;
    if (d >= N) return;
    int h = lane >> 3;
    int beg = offsets[d], end = offsets[d+1];
    int deg = end - beg;
    float sum = 0.f, acc = 0.f;
    if (deg <= MAXDEG) {
        // prologue: p[(e,h')] for all deg*8 pairs; lane -> (e = idx>>3, h' = idx&7)
        float adp = aD[(size_t)d*8 + (lane & 7)];
        int tot = deg * 8;
        for (int base = 0; base < tot; base += 64) {
            int idx = base + lane;
            if (idx < tot) {
                int s = ss[beg + (idx >> 3)];
                pl[w][idx] = __expf(lrelu(aS[(size_t)s*8 + (lane & 7)] + adp));
            }
        }
        for (int j = lane; j < deg; j += 64) sl[w][j] = ss[beg + j];
        // main: per edge = 2 LDS broadcast reads + 1 coalesced h2 row load + fma
        int e = 0;
        for (; e + 4 <= deg; e += 4) {
            int s0 = sl[w][e], s1 = sl[w][e+1], s2 = sl[w][e+2], s3 = sl[w][e+3];
            float p0 = pl[w][e*8 + h],     p1 = pl[w][(e+1)*8 + h];
            float p2 = pl[w][(e+2)*8 + h], p3 = pl[w][(e+3)*8 + h];
            float g0 = h2[(size_t)s0*64 + lane], g1 = h2[(size_t)s1*64 + lane];
            float g2 = h2[(size_t)s2*64 + lane], g3 = h2[(size_t)s3*64 + lane];
            acc += p0*g0 + p1*g1 + p2*g2 + p3*g3;
            sum += (p0 + p1) + (p2 + p3);
        }
        for (; e < deg; ++e) {
            int s = sl[w][e];
            float p = pl[w][e*8 + h];
            sum += p;
            acc += p * h2[(size_t)s*64 + lane];
        }
    } else {
        // fallback (statistically never for Poisson(17)): inline recompute
        float adh = aD[(size_t)d*8 + h];
        for (int e = beg; e < end; ++e) {
            int s = ss[e];
            float p = __expf(lrelu(aS[(size_t)s*8 + h] + adh));
            sum += p;
            acc += p * h2[(size_t)s*64 + lane];
        }
    }
    float r = acc / (sum + SEPS);
    float tt = elu1(r + b2[lane]) * fcw[lane];
    #pragma unroll
    for (int m = 32; m; m >>= 1) tt += __shfl_xor(tt, m);
    if (lane == 0) out[d] = tt + fcb[0];
}

extern "C" void kernel_launch(void* const* d_in, const int* in_sizes, int n_in,
                              void* d_out, int out_size, void* d_ws, size_t ws_size,
                              hipStream_t stream) {
    const float* x    = (const float*)d_in[0];
    const int*   ei   = (const int*)  d_in[1];
    const float* W1   = (const float*)d_in[2];
    const float* as1  = (const float*)d_in[3];
    const float* ad1  = (const float*)d_in[4];
    const float* b1   = (const float*)d_in[5];
    const float* W2   = (const float*)d_in[6];
    const float* attS2= (const float*)d_in[7];
    const float* attD2= (const float*)d_in[8];
    const float* b2   = (const float*)d_in[9];
    const float* fcw  = (const float*)d_in[10];
    const float* fcb  = (const float*)d_in[11];
    float* out = (float*)d_out;

    int N = in_sizes[0];          // x is [N,1]
    int E = in_sizes[1] / 2;      // edge_index is [2,E]
    int ET = E + N;               // with self-loops
    int NB = (N + BSZ - 1) / BSZ; // coarse buckets (<= NBMAX)

    const int* srcI = ei;
    const int* dstI = ei + E;

    float* ws = (float*)d_ws;
    size_t off = 0;
    float* SD           = ws + off; off += 16;
    int*   bucketCnt    = (int*)(ws + off); off += NBMAX;
    int*   bucketBase   = (int*)(ws + off); off += NBMAX + 16;
    int*   bucketCursor = (int*)(ws + off); off += NBMAX;
    int*   blkCnt       = (int*)(ws + off); off += (size_t)NCHUNK * NBMAX;
    int*   offsets      = (int*)(ws + off); off += (size_t)N + 16;
    int*   pk           = (int*)(ws + off); off += (size_t)ET;
    int*   sortedSrc    = (int*)(ws + off); off += (size_t)ET;
    float* aS2          = ws + off; off += (size_t)N * 8;
    float* aD2          = ws + off; off += (size_t)N * 8;
    float* h2           = ws + off; off += (size_t)N * 64;

    hipMemsetAsync(bucketCnt, 0, NBMAX * sizeof(int), stream);

    k_prep1<<<1, 64, 0, stream>>>(W1, as1, ad1, SD);

    int chunk = (ET + NCHUNK - 1) / NCHUNK;
    k_bhist   <<<NCHUNK, TPB, 0, stream>>>(dstI, E, N, NB, chunk, bucketCnt, blkCnt);
    k_bscan   <<<1, NBMAX, 0, stream>>>(bucketCnt, bucketBase, bucketCursor, NB, ET, offsets, N);
    k_bscatter<<<NCHUNK, TPB, 0, stream>>>(srcI, dstI, E, N, NB, chunk, blkCnt, bucketCursor, pk);
    k_mega    <<<NB, BSZ, 0, stream>>>(pk, bucketBase, x, SD, W1, b1, W2, attS2, attD2,
                                       N, offsets, sortedSrc, h2, aS2, aD2);
    k_agg     <<<(N + 3) / 4, TPB, 0, stream>>>(offsets, sortedSrc, aS2, aD2, h2,
                                                b2, fcw, fcb, out, N);
}

// Round 8
// 271.168 us; speedup vs baseline: 1.2951x; 1.0555x over previous
//
#include <hip/hip_runtime.h>
#include <hip/hip_fp16.h>
#include <cmath>

#define TPB 256
#define NSLOPE 0.2f
#define SEPS 1e-16f

#define BSH 8                 // nodes per bucket = 256
#define BSZ 256
#define NBMAX 1024            // supports N up to 262144
#define NCHUNK 256            // blocks for bucket hist/scatter
#define MAXDEG 96             // per-wave LDS score staging cap (P[deg>96] ~ 0 for Poisson(17))

__device__ __forceinline__ float lrelu(float v) { return v > 0.f ? v : NSLOPE * v; }
__device__ __forceinline__ float elu1(float v)  { return v > 0.f ? v : expm1f(v); }

// ---- prep: SD[0..3]=S1[h], SD[4..7]=D1[h]; also zeroes bucketCnt (replaces memset) ----
__global__ void k_prep1(const float* __restrict__ W1, const float* __restrict__ as1,
                        const float* __restrict__ ad1, float* __restrict__ SD,
                        int* __restrict__ bucketCnt) {
    int t = threadIdx.x;
    for (int i = t; i < NBMAX; i += blockDim.x) bucketCnt[i] = 0;
    if (t < 8) {
        int h = t & 3;
        const float* att = (t >= 4) ? ad1 : as1;
        float acc = 0.f;
        #pragma unroll
        for (int c = 0; c < 8; ++c) acc += W1[h*8+c] * att[h*8+c];
        SD[t] = acc;
    }
}

// ---- pass A: coarse bucket histogram; persists per-(block,bucket) counts ----
__global__ void k_bhist(const int* __restrict__ dstI, int E, int N, int NB, int chunk,
                        int* __restrict__ bucketCnt, int* __restrict__ blkCnt) {
    __shared__ int cnt[NBMAX];
    for (int i = threadIdx.x; i < NB; i += blockDim.x) cnt[i] = 0;
    __syncthreads();
    int ET = E + N;
    int beg = blockIdx.x * chunk;
    int end = min(beg + chunk, ET);
    for (int e = beg + threadIdx.x; e < end; e += blockDim.x) {
        int d = (e < E) ? dstI[e] : (e - E);
        atomicAdd(&cnt[d >> BSH], 1);
    }
    __syncthreads();
    int* myBlk = blkCnt + (size_t)blockIdx.x * NBMAX;
    for (int i = threadIdx.x; i < NB; i += blockDim.x) {
        int c = cnt[i];
        myBlk[i] = c;
        if (c) atomicAdd(&bucketCnt[i], c);
    }
}

// ---- pass B: one-block exclusive scan of bucket counts ----
__global__ void k_bscan(const int* __restrict__ bucketCnt, int* __restrict__ bucketBase,
                        int* __restrict__ bucketCursor, int NB, int ET,
                        int* __restrict__ offsets, int N) {
    __shared__ int tmp[NBMAX];
    int t = threadIdx.x;
    int v = (t < NB) ? bucketCnt[t] : 0;
    tmp[t] = v;
    __syncthreads();
    for (int off = 1; off < NBMAX; off <<= 1) {
        int u = (t >= off) ? tmp[t - off] : 0;
        __syncthreads();
        tmp[t] += u;
        __syncthreads();
    }
    if (t < NB) { int ex = tmp[t] - v; bucketBase[t] = ex; bucketCursor[t] = ex; }
    if (t == 0) { bucketBase[NB] = ET; offsets[N] = ET; }
}

// ---- pass C: bucket scatter of packed (src<<8|dstLow); counts pre-read from blkCnt ----
__global__ void k_bscatter(const int* __restrict__ srcI, const int* __restrict__ dstI,
                           int E, int N, int NB, int chunk,
                           const int* __restrict__ blkCnt,
                           int* __restrict__ bucketCursor, int* __restrict__ pk) {
    __shared__ int cnt[NBMAX];
    __shared__ int base[NBMAX];
    const int* myBlk = blkCnt + (size_t)blockIdx.x * NBMAX;
    for (int i = threadIdx.x; i < NB; i += blockDim.x) {
        int c = myBlk[i];
        base[i] = c ? atomicAdd(&bucketCursor[i], c) : 0;
        cnt[i] = 0;
    }
    __syncthreads();
    int ET = E + N;
    int beg = blockIdx.x * chunk;
    int end = min(beg + chunk, ET);
    for (int e = beg + threadIdx.x; e < end; e += blockDim.x) {
        int s, d;
        if (e < E) { s = srcI[e]; d = dstI[e]; } else { s = d = e - E; }
        int b = d >> BSH;
        int r = atomicAdd(&cnt[b], 1);
        pk[base[b] + r] = (s << BSH) | (d & (BSZ - 1));
    }
}

// ---- mega: per-bucket fine sort + layer-1 softmax + h2/att, all in one block ----
__global__ void k_mega(const int* __restrict__ pk, const int* __restrict__ bucketBase,
                       const float* __restrict__ x, const float* __restrict__ SD,
                       const float* __restrict__ W1, const float* __restrict__ b1,
                       const float* __restrict__ W2, const float* __restrict__ attS,
                       const float* __restrict__ attD, int N,
                       int* __restrict__ offsets, int* __restrict__ sortedSrc,
                       __half* __restrict__ h2h, float* __restrict__ aS, float* __restrict__ aD) {
    __shared__ int cnt[BSZ];
    __shared__ int offl[BSZ];
    __shared__ float lds1[BSZ][33];       // +1 pad: conflict-free row writes
    __shared__ float ldsW2[32 * 64];
    int b = blockIdx.x;
    int t = threadIdx.x;
    int rbeg = bucketBase[b], rend = bucketBase[b + 1];
    for (int i = t; i < 2048; i += BSZ) ldsW2[i] = W2[i];
    cnt[t] = 0;
    __syncthreads();
    // phase 1a: fine histogram
    for (int i = rbeg + t; i < rend; i += BSZ)
        atomicAdd(&cnt[pk[i] & (BSZ - 1)], 1);
    __syncthreads();
    int v = cnt[t];
    offl[t] = v;
    __syncthreads();
    for (int off = 1; off < BSZ; off <<= 1) {
        int u = (t >= off) ? offl[t - off] : 0;
        __syncthreads();
        offl[t] += u;
        __syncthreads();
    }
    int ex = offl[t] - v;                 // exclusive prefix within bucket
    int myBeg = rbeg + ex, myEnd = myBeg + v;
    int d = (b << BSH) + t;
    if (d < N) offsets[d] = myBeg;
    cnt[t] = 0;                           // reuse as per-node cursor
    offl[t] = ex;
    __syncthreads();
    // phase 1b: scatter src into bucket-local sorted order
    for (int i = rbeg + t; i < rend; i += BSZ) {
        int p = pk[i];
        int dl = p & (BSZ - 1);
        int r = atomicAdd(&cnt[dl], 1);
        sortedSrc[rbeg + offl[dl] + r] = p >> BSH;
    }
    __syncthreads();
    // phase 2: layer-1 softmax for node d (thread-per-node)
    if (d < N) {
        float xd = x[d];
        float S0 = SD[0], S1 = SD[1], S2 = SD[2], S3 = SD[3];
        float D0 = xd*SD[4], D1 = xd*SD[5], D2 = xd*SD[6], D3 = xd*SD[7];
        float s0 = 0.f, s1 = 0.f, s2 = 0.f, s3 = 0.f;
        float g0 = 0.f, g1 = 0.f, g2 = 0.f, g3 = 0.f;
        for (int i = myBeg; i < myEnd; ++i) {
            float xs = x[sortedSrc[i]];
            float p;
            p = __expf(lrelu(xs*S0 + D0)); s0 += p; g0 += p * xs;
            p = __expf(lrelu(xs*S1 + D1)); s1 += p; g1 += p * xs;
            p = __expf(lrelu(xs*S2 + D2)); s2 += p; g2 += p * xs;
            p = __expf(lrelu(xs*S3 + D3)); s3 += p; g3 += p * xs;
        }
        float gg[4];
        gg[0] = g0 / (s0 + SEPS); gg[1] = g1 / (s1 + SEPS);
        gg[2] = g2 / (s2 + SEPS); gg[3] = g3 / (s3 + SEPS);
        #pragma unroll
        for (int hh = 0; hh < 4; ++hh)
            #pragma unroll
            for (int cc = 0; cc < 8; ++cc)
                lds1[t][hh*8+cc] = elu1(gg[hh] * W1[hh*8+cc] + b1[hh*8+cc]);
    }
    __syncthreads();
    // phase 3: h2 = lds1 @ W2 (+ att coeffs); one node per wave per round.
    // aS/aD computed in fp32 from unrounded acc; h2 stored fp16 for the gather phase.
    int lane = t & 63;                    // channel j
    int sub = t >> 6;                     // wave id 0..3
    int nCnt = min(BSZ, N - (b << BSH));
    float attSl = attS[lane], attDl = attD[lane];
    for (int nn = sub; nn < nCnt; nn += 4) {
        const float* row = lds1[nn];
        float acc = 0.f;
        #pragma unroll
        for (int k = 0; k < 32; ++k) acc += row[k] * ldsW2[k*64 + lane];
        int node = (b << BSH) + nn;
        h2h[(size_t)node*64 + lane] = __float2half(acc);
        float ps = acc * attSl;
        float pd = acc * attDl;
        #pragma unroll
        for (int m = 1; m < 8; m <<= 1) {
            ps += __shfl_xor(ps, m);
            pd += __shfl_xor(pd, m);
        }
        int hh = lane >> 3, cc = lane & 7;
        if (cc == 0) aS[(size_t)node*8 + hh] = ps;
        if (cc == 1) aD[(size_t)node*8 + hh] = pd;
    }
}

// ---- layer 2: wave-per-node; scores staged in LDS (64 distinct exps/wave-instr),
//      h2 gathered as fp16 rows (128B/edge, half the fabric traffic) ----
__global__ void k_agg(const int* __restrict__ offsets, const int* __restrict__ ss,
                      const float* __restrict__ aS, const float* __restrict__ aD,
                      const __half* __restrict__ h2h, const float* __restrict__ b2,
                      const float* __restrict__ fcw, const float* __restrict__ fcb,
                      float* __restrict__ out, int N) {
    __shared__ float pl[4][MAXDEG * 8];
    __shared__ int   sl[4][MAXDEG];
    int lane = threadIdx.x & 63;
    int w = threadIdx.x >> 6;
    int d = blockIdx.x * 4 + w;
    if (d >= N) return;
    int h = lane >> 3;
    int beg = offsets[d], end = offsets[d+1];
    int deg = end - beg;
    float sum = 0.f, acc = 0.f;
    if (deg <= MAXDEG) {
        // prologue: p[(e,h')] for all deg*8 pairs; lane -> (e = idx>>3, h' = idx&7)
        float adp = aD[(size_t)d*8 + (lane & 7)];
        int tot = deg * 8;
        for (int base = 0; base < tot; base += 64) {
            int idx = base + lane;
            if (idx < tot) {
                int s = ss[beg + (idx >> 3)];
                pl[w][idx] = __expf(lrelu(aS[(size_t)s*8 + (lane & 7)] + adp));
            }
        }
        for (int j = lane; j < deg; j += 64) sl[w][j] = ss[beg + j];
        // main: per edge = 2 LDS broadcast reads + 1 coalesced fp16 row load + cvt + fma
        int e = 0;
        for (; e + 4 <= deg; e += 4) {
            int s0 = sl[w][e], s1 = sl[w][e+1], s2 = sl[w][e+2], s3 = sl[w][e+3];
            float p0 = pl[w][e*8 + h],     p1 = pl[w][(e+1)*8 + h];
            float p2 = pl[w][(e+2)*8 + h], p3 = pl[w][(e+3)*8 + h];
            float g0 = __half2float(h2h[(size_t)s0*64 + lane]);
            float g1 = __half2float(h2h[(size_t)s1*64 + lane]);
            float g2 = __half2float(h2h[(size_t)s2*64 + lane]);
            float g3 = __half2float(h2h[(size_t)s3*64 + lane]);
            acc += p0*g0 + p1*g1 + p2*g2 + p3*g3;
            sum += (p0 + p1) + (p2 + p3);
        }
        for (; e < deg; ++e) {
            int s = sl[w][e];
            float p = pl[w][e*8 + h];
            sum += p;
            acc += p * __half2float(h2h[(size_t)s*64 + lane]);
        }
    } else {
        // fallback (statistically never for Poisson(17)): inline recompute
        float adh = aD[(size_t)d*8 + h];
        for (int e = beg; e < end; ++e) {
            int s = ss[e];
            float p = __expf(lrelu(aS[(size_t)s*8 + h] + adh));
            sum += p;
            acc += p * __half2float(h2h[(size_t)s*64 + lane]);
        }
    }
    float r = acc / (sum + SEPS);
    float tt = elu1(r + b2[lane]) * fcw[lane];
    #pragma unroll
    for (int m = 32; m; m >>= 1) tt += __shfl_xor(tt, m);
    if (lane == 0) out[d] = tt + fcb[0];
}

extern "C" void kernel_launch(void* const* d_in, const int* in_sizes, int n_in,
                              void* d_out, int out_size, void* d_ws, size_t ws_size,
                              hipStream_t stream) {
    const float* x    = (const float*)d_in[0];
    const int*   ei   = (const int*)  d_in[1];
    const float* W1   = (const float*)d_in[2];
    const float* as1  = (const float*)d_in[3];
    const float* ad1  = (const float*)d_in[4];
    const float* b1   = (const float*)d_in[5];
    const float* W2   = (const float*)d_in[6];
    const float* attS2= (const float*)d_in[7];
    const float* attD2= (const float*)d_in[8];
    const float* b2   = (const float*)d_in[9];
    const float* fcw  = (const float*)d_in[10];
    const float* fcb  = (const float*)d_in[11];
    float* out = (float*)d_out;

    int N = in_sizes[0];          // x is [N,1]
    int E = in_sizes[1] / 2;      // edge_index is [2,E]
    int ET = E + N;               // with self-loops
    int NB = (N + BSZ - 1) / BSZ; // coarse buckets (<= NBMAX)

    const int* srcI = ei;
    const int* dstI = ei + E;

    float* ws = (float*)d_ws;
    size_t off = 0;
    float* SD           = ws + off; off += 16;
    int*   bucketCnt    = (int*)(ws + off); off += NBMAX;
    int*   bucketBase   = (int*)(ws + off); off += NBMAX + 16;
    int*   bucketCursor = (int*)(ws + off); off += NBMAX;
    int*   blkCnt       = (int*)(ws + off); off += (size_t)NCHUNK * NBMAX;
    int*   offsets      = (int*)(ws + off); off += (size_t)N + 16;
    int*   pk           = (int*)(ws + off); off += (size_t)ET;
    int*   sortedSrc    = (int*)(ws + off); off += (size_t)ET;
    float* aS2          = ws + off; off += (size_t)N * 8;
    float* aD2          = ws + off; off += (size_t)N * 8;
    __half* h2h         = (__half*)(ws + off); off += (size_t)N * 32;  // N*64 halves

    k_prep1<<<1, 256, 0, stream>>>(W1, as1, ad1, SD, bucketCnt);

    int chunk = (ET + NCHUNK - 1) / NCHUNK;
    k_bhist   <<<NCHUNK, TPB, 0, stream>>>(dstI, E, N, NB, chunk, bucketCnt, blkCnt);
    k_bscan   <<<1, NBMAX, 0, stream>>>(bucketCnt, bucketBase, bucketCursor, NB, ET, offsets, N);
    k_bscatter<<<NCHUNK, TPB, 0, stream>>>(srcI, dstI, E, N, NB, chunk, blkCnt, bucketCursor, pk);
    k_mega    <<<NB, BSZ, 0, stream>>>(pk, bucketBase, x, SD, W1, b1, W2, attS2, attD2,
                                       N, offsets, sortedSrc, h2h, aS2, aD2);
    k_agg     <<<(N + 3) / 4, TPB, 0, stream>>>(offsets, sortedSrc, aS2, aD2, h2h,
                                                b2, fcw, fcb, out, N);
}

// Round 9
// 249.010 us; speedup vs baseline: 1.4103x; 1.0890x over previous
//
#include <hip/hip_runtime.h>
#include <hip/hip_fp16.h>
#include <cmath>

#define TPB 256
#define NSLOPE 0.2f
#define SEPS 1e-16f

#define BSH 8                 // nodes per bucket = 256
#define BSZ 256
#define NBMAX 1024            // supports N up to 262144
#define NCHUNK 256            // blocks for bucket scatter
#define MAXDEG 96             // per-wave LDS score staging cap (P[deg>96] ~ 0 for Poisson(17))

__device__ __forceinline__ float lrelu(float v) { return v > 0.f ? v : NSLOPE * v; }
__device__ __forceinline__ float elu1(float v)  { return v > 0.f ? v : expm1f(v); }

// ---- prep: SD[0..3]=S1[h], SD[4..7]=D1[h]; init padded-bucket cursors ----
__global__ void k_prep(const float* __restrict__ W1, const float* __restrict__ as1,
                       const float* __restrict__ ad1, float* __restrict__ SD,
                       unsigned* __restrict__ bucketCursor, int NB, unsigned cap) {
    int t = threadIdx.x;
    for (int i = t; i < NB; i += blockDim.x) bucketCursor[i] = (unsigned)i * cap;
    if (t < 8) {
        int h = t & 3;
        const float* att = (t >= 4) ? ad1 : as1;
        float acc = 0.f;
        #pragma unroll
        for (int c = 0; c < 8; ++c) acc += W1[h*8+c] * att[h*8+c];
        SD[t] = acc;
    }
}

// ---- bucket scatter into PADDED regions: per-chunk LDS hist -> one claim atomic
//      per (block,bucket) -> write packed (src<<8|dstLow). No global scan needed. ----
__global__ void k_bscatter(const int* __restrict__ srcI, const int* __restrict__ dstI,
                           int E, int N, int NB, int chunk,
                           unsigned* __restrict__ bucketCursor, int* __restrict__ pk) {
    __shared__ int cnt[NBMAX];
    __shared__ unsigned base[NBMAX];
    for (int i = threadIdx.x; i < NB; i += blockDim.x) cnt[i] = 0;
    __syncthreads();
    int ET = E + N;
    int beg = blockIdx.x * chunk;
    int end = min(beg + chunk, ET);
    for (int e = beg + threadIdx.x; e < end; e += blockDim.x) {
        int d = (e < E) ? dstI[e] : (e - E);
        atomicAdd(&cnt[d >> BSH], 1);
    }
    __syncthreads();
    for (int i = threadIdx.x; i < NB; i += blockDim.x) {
        int c = cnt[i];
        base[i] = c ? atomicAdd(&bucketCursor[i], (unsigned)c) : 0u;
        cnt[i] = 0;
    }
    __syncthreads();
    for (int e = beg + threadIdx.x; e < end; e += blockDim.x) {
        int s, d;
        if (e < E) { s = srcI[e]; d = dstI[e]; } else { s = d = e - E; }
        int b = d >> BSH;
        int r = atomicAdd(&cnt[b], 1);
        pk[base[b] + r] = (s << BSH) | (d & (BSZ - 1));
    }
}

// ---- mega: per-bucket fine sort + layer-1 softmax + h2/att, one block per bucket ----
__global__ void k_mega(const int* __restrict__ pk, const unsigned* __restrict__ bucketCursor,
                       unsigned cap,
                       const float* __restrict__ x, const float* __restrict__ SD,
                       const float* __restrict__ W1, const float* __restrict__ b1,
                       const float* __restrict__ W2, const float* __restrict__ attS,
                       const float* __restrict__ attD, int N,
                       unsigned* __restrict__ offsets, int* __restrict__ sortedSrc,
                       __half* __restrict__ h2h, float* __restrict__ aS, float* __restrict__ aD) {
    __shared__ int cnt[BSZ];
    __shared__ int offl[BSZ];
    __shared__ float lds1[BSZ][33];       // +1 pad: conflict-free row writes
    int b = blockIdx.x;
    int t = threadIdx.x;
    unsigned rbeg = (unsigned)b * cap, rend = bucketCursor[b];
    cnt[t] = 0;
    __syncthreads();
    // phase 1a: fine histogram
    for (unsigned i = rbeg + t; i < rend; i += BSZ)
        atomicAdd(&cnt[pk[i] & (BSZ - 1)], 1);
    __syncthreads();
    int v = cnt[t];
    offl[t] = v;
    __syncthreads();
    for (int off = 1; off < BSZ; off <<= 1) {
        int u = (t >= off) ? offl[t - off] : 0;
        __syncthreads();
        offl[t] += u;
        __syncthreads();
    }
    int ex = offl[t] - v;                 // exclusive prefix within bucket
    unsigned myBeg = rbeg + (unsigned)ex;
    int d = (b << BSH) + t;
    if (d < N) offsets[d] = (myBeg << 10) | (unsigned)v;   // packed (beg,deg)
    cnt[t] = 0;                           // reuse as per-node cursor
    offl[t] = ex;
    __syncthreads();
    // phase 1b: scatter src into bucket-local sorted order
    for (unsigned i = rbeg + t; i < rend; i += BSZ) {
        int p = pk[i];
        int dl = p & (BSZ - 1);
        int r = atomicAdd(&cnt[dl], 1);
        sortedSrc[rbeg + (unsigned)(offl[dl] + r)] = p >> BSH;
    }
    __syncthreads();
    // phase 2: layer-1 softmax for node d (thread-per-node)
    if (d < N) {
        float xd = x[d];
        float S0 = SD[0], S1 = SD[1], S2 = SD[2], S3 = SD[3];
        float D0 = xd*SD[4], D1 = xd*SD[5], D2 = xd*SD[6], D3 = xd*SD[7];
        float s0 = 0.f, s1 = 0.f, s2 = 0.f, s3 = 0.f;
        float g0 = 0.f, g1 = 0.f, g2 = 0.f, g3 = 0.f;
        unsigned myEnd = myBeg + (unsigned)v;
        for (unsigned i = myBeg; i < myEnd; ++i) {
            float xs = x[sortedSrc[i]];
            float p;
            p = __expf(lrelu(xs*S0 + D0)); s0 += p; g0 += p * xs;
            p = __expf(lrelu(xs*S1 + D1)); s1 += p; g1 += p * xs;
            p = __expf(lrelu(xs*S2 + D2)); s2 += p; g2 += p * xs;
            p = __expf(lrelu(xs*S3 + D3)); s3 += p; g3 += p * xs;
        }
        float gg[4];
        gg[0] = g0 / (s0 + SEPS); gg[1] = g1 / (s1 + SEPS);
        gg[2] = g2 / (s2 + SEPS); gg[3] = g3 / (s3 + SEPS);
        #pragma unroll
        for (int hh = 0; hh < 4; ++hh)
            #pragma unroll
            for (int cc = 0; cc < 8; ++cc)
                lds1[t][hh*8+cc] = elu1(gg[hh] * W1[hh*8+cc] + b1[hh*8+cc]);
    }
    __syncthreads();
    // phase 3: h2 = lds1 @ W2 (+ att coeffs); W2 column held in 32 VGPRs per lane.
    int lane = t & 63;                    // channel j
    int sub = t >> 6;                     // wave id 0..3
    float w2r[32];
    #pragma unroll
    for (int k = 0; k < 32; ++k) w2r[k] = W2[k*64 + lane];
    float attSl = attS[lane], attDl = attD[lane];
    int nCnt = min(BSZ, N - (b << BSH));
    for (int nn = sub; nn < nCnt; nn += 4) {
        const float* row = lds1[nn];
        float acc = 0.f;
        #pragma unroll
        for (int k = 0; k < 32; ++k) acc += row[k] * w2r[k];
        int node = (b << BSH) + nn;
        h2h[(size_t)node*64 + lane] = __float2half(acc);
        float ps = acc * attSl;
        float pd = acc * attDl;
        #pragma unroll
        for (int m = 1; m < 8; m <<= 1) {
            ps += __shfl_xor(ps, m);
            pd += __shfl_xor(pd, m);
        }
        int hh = lane >> 3, cc = lane & 7;
        if (cc == 0) aS[(size_t)node*8 + hh] = ps;
        if (cc == 1) aD[(size_t)node*8 + hh] = pd;
    }
}

// ---- layer 2: wave-per-node; src list staged to LDS once, scores computed from LDS
//      (64 distinct exps/wave-instr), fp16 h2 row gather (128B/edge) ----
__global__ void k_agg(const unsigned* __restrict__ offsets, const int* __restrict__ ss,
                      const float* __restrict__ aS, const float* __restrict__ aD,
                      const __half* __restrict__ h2h, const float* __restrict__ b2,
                      const float* __restrict__ fcw, const float* __restrict__ fcb,
                      float* __restrict__ out, int N) {
    __shared__ float pl[4][MAXDEG * 8];
    __shared__ int   sl[4][MAXDEG];
    int lane = threadIdx.x & 63;
    int w = threadIdx.x >> 6;
    int d = blockIdx.x * 4 + w;
    if (d >= N) return;
    int h = lane >> 3;
    unsigned u = offsets[d];
    unsigned beg = u >> 10;
    int deg = (int)(u & 1023u);
    float sum = 0.f, acc = 0.f;
    if (deg <= MAXDEG) {
        // stage src list (coalesced), then scores from LDS
        for (int j = lane; j < deg; j += 64) sl[w][j] = ss[beg + j];
        float adp = aD[(size_t)d*8 + (lane & 7)];
        int tot = deg * 8;
        for (int base = 0; base < tot; base += 64) {
            int idx = base + lane;
            if (idx < tot) {
                int s = sl[w][idx >> 3];
                pl[w][idx] = __expf(lrelu(aS[(size_t)s*8 + (lane & 7)] + adp));
            }
        }
        // main: per edge = 2 LDS broadcast reads + 1 coalesced fp16 row load + cvt + fma
        int e = 0;
        for (; e + 4 <= deg; e += 4) {
            int s0 = sl[w][e], s1 = sl[w][e+1], s2 = sl[w][e+2], s3 = sl[w][e+3];
            float p0 = pl[w][e*8 + h],     p1 = pl[w][(e+1)*8 + h];
            float p2 = pl[w][(e+2)*8 + h], p3 = pl[w][(e+3)*8 + h];
            float g0 = __half2float(h2h[(size_t)s0*64 + lane]);
            float g1 = __half2float(h2h[(size_t)s1*64 + lane]);
            float g2 = __half2float(h2h[(size_t)s2*64 + lane]);
            float g3 = __half2float(h2h[(size_t)s3*64 + lane]);
            acc += p0*g0 + p1*g1 + p2*g2 + p3*g3;
            sum += (p0 + p1) + (p2 + p3);
        }
        for (; e < deg; ++e) {
            int s = sl[w][e];
            float p = pl[w][e*8 + h];
            sum += p;
            acc += p * __half2float(h2h[(size_t)s*64 + lane]);
        }
    } else {
        // fallback (statistically never for Poisson(17)): inline recompute
        float adh = aD[(size_t)d*8 + h];
        for (unsigned e = beg; e < beg + (unsigned)deg; ++e) {
            int s = ss[e];
            float p = __expf(lrelu(aS[(size_t)s*8 + h] + adh));
            sum += p;
            acc += p * __half2float(h2h[(size_t)s*64 + lane]);
        }
    }
    float r = acc / (sum + SEPS);
    float tt = elu1(r + b2[lane]) * fcw[lane];
    #pragma unroll
    for (int m = 32; m; m >>= 1) tt += __shfl_xor(tt, m);
    if (lane == 0) out[d] = tt + fcb[0];
}

extern "C" void kernel_launch(void* const* d_in, const int* in_sizes, int n_in,
                              void* d_out, int out_size, void* d_ws, size_t ws_size,
                              hipStream_t stream) {
    const float* x    = (const float*)d_in[0];
    const int*   ei   = (const int*)  d_in[1];
    const float* W1   = (const float*)d_in[2];
    const float* as1  = (const float*)d_in[3];
    const float* ad1  = (const float*)d_in[4];
    const float* b1   = (const float*)d_in[5];
    const float* W2   = (const float*)d_in[6];
    const float* attS2= (const float*)d_in[7];
    const float* attD2= (const float*)d_in[8];
    const float* b2   = (const float*)d_in[9];
    const float* fcw  = (const float*)d_in[10];
    const float* fcb  = (const float*)d_in[11];
    float* out = (float*)d_out;

    int N = in_sizes[0];          // x is [N,1]
    int E = in_sizes[1] / 2;      // edge_index is [2,E]
    int ET = E + N;               // with self-loops
    int NB = (N + BSZ - 1) / BSZ; // coarse buckets (<= NBMAX)
    // padded bucket capacity: mean + 1024 (~13 sigma for Binomial(ET, 1/NB)), 4-aligned
    unsigned cap = (unsigned)((ET + NB - 1) / NB + 1024);
    cap = (cap + 3u) & ~3u;
    size_t padded = (size_t)NB * cap;

    const int* srcI = ei;
    const int* dstI = ei + E;

    float* ws = (float*)d_ws;
    size_t off = 0;
    float*    SD           = ws + off; off += 16;
    unsigned* bucketCursor = (unsigned*)(ws + off); off += NBMAX;
    unsigned* offsets      = (unsigned*)(ws + off); off += (size_t)N + 16;
    int*      pk           = (int*)(ws + off); off += padded;
    int*      sortedSrc    = (int*)(ws + off); off += padded;
    float*    aS2          = ws + off; off += (size_t)N * 8;
    float*    aD2          = ws + off; off += (size_t)N * 8;
    __half*   h2h          = (__half*)(ws + off); off += (size_t)N * 32;  // N*64 halves

    k_prep<<<1, 1024, 0, stream>>>(W1, as1, ad1, SD, bucketCursor, NB, cap);

    int chunk = (ET + NCHUNK - 1) / NCHUNK;
    k_bscatter<<<NCHUNK, TPB, 0, stream>>>(srcI, dstI, E, N, NB, chunk, bucketCursor, pk);
    k_mega    <<<NB, BSZ, 0, stream>>>(pk, bucketCursor, cap, x, SD, W1, b1, W2, attS2, attD2,
                                       N, offsets, sortedSrc, h2h, aS2, aD2);
    k_agg     <<<(N + 3) / 4, TPB, 0, stream>>>(offsets, sortedSrc, aS2, aD2, h2h,
                                                b2, fcw, fcb, out, N);
}

// Round 10
// 234.714 us; speedup vs baseline: 1.4962x; 1.0609x over previous
//
#include <hip/hip_runtime.h>
#include <hip/hip_fp16.h>
#include <cmath>

#define TPB 256
#define NSLOPE 0.2f
#define SEPS 1e-16f

#define BSH 7                 // nodes per bucket = 128
#define BNODES 128
#define BSZ 256               // threads per mega/sort block
#define NBMAX 1024            // supports N up to 131072 at BSH=7
#define NCHUNK 512            // blocks for bucket scatter
#define MAXDEG 96             // per-wave LDS score staging cap (P[deg>96] ~ 0 for Poisson(17))

__device__ __forceinline__ float lrelu(float v) { return v > 0.f ? v : NSLOPE * v; }
__device__ __forceinline__ float elu1(float v)  { return v > 0.f ? v : expm1f(v); }

// ---- prep: SD[0..3]=S1[h], SD[4..7]=D1[h]; init padded-bucket cursors ----
__global__ void k_prep(const float* __restrict__ W1, const float* __restrict__ as1,
                       const float* __restrict__ ad1, float* __restrict__ SD,
                       unsigned* __restrict__ bucketCursor, int NB, unsigned cap) {
    int t = threadIdx.x;
    for (int i = t; i < NB; i += blockDim.x) bucketCursor[i] = (unsigned)i * cap;
    if (t < 8) {
        int h = t & 3;
        const float* att = (t >= 4) ? ad1 : as1;
        float acc = 0.f;
        #pragma unroll
        for (int c = 0; c < 8; ++c) acc += W1[h*8+c] * att[h*8+c];
        SD[t] = acc;
    }
}

// ---- bucket scatter into PADDED regions: per-chunk LDS hist -> one claim atomic
//      per (block,bucket) -> write packed (src<<7|dstLow). ----
__global__ void k_bscatter(const int* __restrict__ srcI, const int* __restrict__ dstI,
                           int E, int N, int NB, int chunk,
                           unsigned* __restrict__ bucketCursor, int* __restrict__ pk) {
    __shared__ int cnt[NBMAX];
    __shared__ unsigned base[NBMAX];
    for (int i = threadIdx.x; i < NB; i += blockDim.x) cnt[i] = 0;
    __syncthreads();
    int ET = E + N;
    int beg = blockIdx.x * chunk;
    int end = min(beg + chunk, ET);
    for (int e = beg + threadIdx.x; e < end; e += blockDim.x) {
        int d = (e < E) ? dstI[e] : (e - E);
        atomicAdd(&cnt[d >> BSH], 1);
    }
    __syncthreads();
    for (int i = threadIdx.x; i < NB; i += blockDim.x) {
        int c = cnt[i];
        base[i] = c ? atomicAdd(&bucketCursor[i], (unsigned)c) : 0u;
        cnt[i] = 0;
    }
    __syncthreads();
    for (int e = beg + threadIdx.x; e < end; e += blockDim.x) {
        int s, d;
        if (e < E) { s = srcI[e]; d = dstI[e]; } else { s = d = e - E; }
        int b = d >> BSH;
        int r = atomicAdd(&cnt[b], 1);
        pk[base[b] + r] = (s << BSH) | (d & (BNODES - 1));
    }
}

// ---- mega: per-bucket fine sort + layer-1 softmax + h2/att, one block per bucket ----
__global__ void k_mega(const int* __restrict__ pk, const unsigned* __restrict__ bucketCursor,
                       unsigned cap,
                       const float* __restrict__ x, const float* __restrict__ SD,
                       const float* __restrict__ W1, const float* __restrict__ b1,
                       const float* __restrict__ W2, const float* __restrict__ attS,
                       const float* __restrict__ attD, int N,
                       unsigned* __restrict__ offsets, int* __restrict__ sortedSrc,
                       __half* __restrict__ h2h, float* __restrict__ aS, float* __restrict__ aD) {
    __shared__ int cnt[BSZ];
    __shared__ int offl[BSZ];
    __shared__ float lds1[BNODES][33];    // +1 pad: conflict-free row writes
    int b = blockIdx.x;
    int t = threadIdx.x;
    unsigned rbeg = (unsigned)b * cap, rend = bucketCursor[b];
    cnt[t] = 0;
    __syncthreads();
    // phase 1a: fine histogram (dl in [0,128))
    for (unsigned i = rbeg + t; i < rend; i += BSZ)
        atomicAdd(&cnt[pk[i] & (BNODES - 1)], 1);
    __syncthreads();
    int v = cnt[t];
    offl[t] = v;
    __syncthreads();
    for (int off = 1; off < BSZ; off <<= 1) {
        int u = (t >= off) ? offl[t - off] : 0;
        __syncthreads();
        offl[t] += u;
        __syncthreads();
    }
    int ex = offl[t] - v;                 // exclusive prefix within bucket
    unsigned myBeg = rbeg + (unsigned)ex;
    int d = (b << BSH) + t;
    if (t < BNODES && d < N) offsets[d] = (myBeg << 10) | (unsigned)v;  // packed (beg,deg)
    cnt[t] = 0;                           // reuse as per-node cursor
    offl[t] = ex;
    __syncthreads();
    // phase 1b: scatter src into bucket-local sorted order
    for (unsigned i = rbeg + t; i < rend; i += BSZ) {
        int p = pk[i];
        int dl = p & (BNODES - 1);
        int r = atomicAdd(&cnt[dl], 1);
        sortedSrc[rbeg + (unsigned)(offl[dl] + r)] = p >> BSH;
    }
    __syncthreads();
    // phase 2: layer-1 softmax for node d (thread-per-node, 4x unrolled for MLP)
    if (t < BNODES && d < N) {
        float xd = x[d];
        float S0 = SD[0], S1 = SD[1], S2 = SD[2], S3 = SD[3];
        float D0 = xd*SD[4], D1 = xd*SD[5], D2 = xd*SD[6], D3 = xd*SD[7];
        float s0 = 0.f, s1 = 0.f, s2 = 0.f, s3 = 0.f;
        float g0 = 0.f, g1 = 0.f, g2 = 0.f, g3 = 0.f;
        unsigned i = myBeg;
        int rem = v;
        for (; rem >= 4; rem -= 4, i += 4) {
            int a0 = sortedSrc[i],   a1 = sortedSrc[i+1];
            int a2 = sortedSrc[i+2], a3 = sortedSrc[i+3];
            float x0 = x[a0], x1 = x[a1], x2 = x[a2], x3 = x[a3];
            float p;
            p = __expf(lrelu(x0*S0 + D0)); s0 += p; g0 += p * x0;
            p = __expf(lrelu(x0*S1 + D1)); s1 += p; g1 += p * x0;
            p = __expf(lrelu(x0*S2 + D2)); s2 += p; g2 += p * x0;
            p = __expf(lrelu(x0*S3 + D3)); s3 += p; g3 += p * x0;
            p = __expf(lrelu(x1*S0 + D0)); s0 += p; g0 += p * x1;
            p = __expf(lrelu(x1*S1 + D1)); s1 += p; g1 += p * x1;
            p = __expf(lrelu(x1*S2 + D2)); s2 += p; g2 += p * x1;
            p = __expf(lrelu(x1*S3 + D3)); s3 += p; g3 += p * x1;
            p = __expf(lrelu(x2*S0 + D0)); s0 += p; g0 += p * x2;
            p = __expf(lrelu(x2*S1 + D1)); s1 += p; g1 += p * x2;
            p = __expf(lrelu(x2*S2 + D2)); s2 += p; g2 += p * x2;
            p = __expf(lrelu(x2*S3 + D3)); s3 += p; g3 += p * x2;
            p = __expf(lrelu(x3*S0 + D0)); s0 += p; g0 += p * x3;
            p = __expf(lrelu(x3*S1 + D1)); s1 += p; g1 += p * x3;
            p = __expf(lrelu(x3*S2 + D2)); s2 += p; g2 += p * x3;
            p = __expf(lrelu(x3*S3 + D3)); s3 += p; g3 += p * x3;
        }
        for (; rem > 0; --rem, ++i) {
            float xs = x[sortedSrc[i]];
            float p;
            p = __expf(lrelu(xs*S0 + D0)); s0 += p; g0 += p * xs;
            p = __expf(lrelu(xs*S1 + D1)); s1 += p; g1 += p * xs;
            p = __expf(lrelu(xs*S2 + D2)); s2 += p; g2 += p * xs;
            p = __expf(lrelu(xs*S3 + D3)); s3 += p; g3 += p * xs;
        }
        float gg[4];
        gg[0] = g0 / (s0 + SEPS); gg[1] = g1 / (s1 + SEPS);
        gg[2] = g2 / (s2 + SEPS); gg[3] = g3 / (s3 + SEPS);
        #pragma unroll
        for (int hh = 0; hh < 4; ++hh)
            #pragma unroll
            for (int cc = 0; cc < 8; ++cc)
                lds1[t][hh*8+cc] = elu1(gg[hh] * W1[hh*8+cc] + b1[hh*8+cc]);
    }
    __syncthreads();
    // phase 3: h2 = lds1 @ W2 (+ att coeffs); W2 column held in 32 VGPRs per lane.
    int lane = t & 63;                    // channel j
    int sub = t >> 6;                     // wave id 0..3
    float w2r[32];
    #pragma unroll
    for (int k = 0; k < 32; ++k) w2r[k] = W2[k*64 + lane];
    float attSl = attS[lane], attDl = attD[lane];
    int nCnt = min(BNODES, N - (b << BSH));
    for (int nn = sub; nn < nCnt; nn += 4) {
        const float* row = lds1[nn];
        float acc = 0.f;
        #pragma unroll
        for (int k = 0; k < 32; ++k) acc += row[k] * w2r[k];
        int node = (b << BSH) + nn;
        h2h[(size_t)node*64 + lane] = __float2half(acc);
        float ps = acc * attSl;
        float pd = acc * attDl;
        #pragma unroll
        for (int m = 1; m < 8; m <<= 1) {
            ps += __shfl_xor(ps, m);
            pd += __shfl_xor(pd, m);
        }
        int hh = lane >> 3, cc = lane & 7;
        if (cc == 0) aS[(size_t)node*8 + hh] = ps;
        if (cc == 1) aD[(size_t)node*8 + hh] = pd;
    }
}

// ---- layer 2: wave-per-node; src list staged to LDS once, scores computed from LDS
//      (64 distinct exps/wave-instr), fp16 h2 row gather (128B/edge) ----
__global__ void k_agg(const unsigned* __restrict__ offsets, const int* __restrict__ ss,
                      const float* __restrict__ aS, const float* __restrict__ aD,
                      const __half* __restrict__ h2h, const float* __restrict__ b2,
                      const float* __restrict__ fcw, const float* __restrict__ fcb,
                      float* __restrict__ out, int N) {
    __shared__ float pl[4][MAXDEG * 8];
    __shared__ int   sl[4][MAXDEG];
    int lane = threadIdx.x & 63;
    int w = threadIdx.x >> 6;
    int d = blockIdx.x * 4 + w;
    if (d >= N) return;
    int h = lane >> 3;
    unsigned u = offsets[d];
    unsigned beg = u >> 10;
    int deg = (int)(u & 1023u);
    float sum = 0.f, acc = 0.f;
    if (deg <= MAXDEG) {
        for (int j = lane; j < deg; j += 64) sl[w][j] = ss[beg + j];
        float adp = aD[(size_t)d*8 + (lane & 7)];
        int tot = deg * 8;
        for (int base = 0; base < tot; base += 64) {
            int idx = base + lane;
            if (idx < tot) {
                int s = sl[w][idx >> 3];
                pl[w][idx] = __expf(lrelu(aS[(size_t)s*8 + (lane & 7)] + adp));
            }
        }
        int e = 0;
        for (; e + 4 <= deg; e += 4) {
            int s0 = sl[w][e], s1 = sl[w][e+1], s2 = sl[w][e+2], s3 = sl[w][e+3];
            float p0 = pl[w][e*8 + h],     p1 = pl[w][(e+1)*8 + h];
            float p2 = pl[w][(e+2)*8 + h], p3 = pl[w][(e+3)*8 + h];
            float g0 = __half2float(h2h[(size_t)s0*64 + lane]);
            float g1 = __half2float(h2h[(size_t)s1*64 + lane]);
            float g2 = __half2float(h2h[(size_t)s2*64 + lane]);
            float g3 = __half2float(h2h[(size_t)s3*64 + lane]);
            acc += p0*g0 + p1*g1 + p2*g2 + p3*g3;
            sum += (p0 + p1) + (p2 + p3);
        }
        for (; e < deg; ++e) {
            int s = sl[w][e];
            float p = pl[w][e*8 + h];
            sum += p;
            acc += p * __half2float(h2h[(size_t)s*64 + lane]);
        }
    } else {
        float adh = aD[(size_t)d*8 + h];
        for (unsigned e = beg; e < beg + (unsigned)deg; ++e) {
            int s = ss[e];
            float p = __expf(lrelu(aS[(size_t)s*8 + h] + adh));
            sum += p;
            acc += p * __half2float(h2h[(size_t)s*64 + lane]);
        }
    }
    float r = acc / (sum + SEPS);
    float tt = elu1(r + b2[lane]) * fcw[lane];
    #pragma unroll
    for (int m = 32; m; m >>= 1) tt += __shfl_xor(tt, m);
    if (lane == 0) out[d] = tt + fcb[0];
}

extern "C" void kernel_launch(void* const* d_in, const int* in_sizes, int n_in,
                              void* d_out, int out_size, void* d_ws, size_t ws_size,
                              hipStream_t stream) {
    const float* x    = (const float*)d_in[0];
    const int*   ei   = (const int*)  d_in[1];
    const float* W1   = (const float*)d_in[2];
    const float* as1  = (const float*)d_in[3];
    const float* ad1  = (const float*)d_in[4];
    const float* b1   = (const float*)d_in[5];
    const float* W2   = (const float*)d_in[6];
    const float* attS2= (const float*)d_in[7];
    const float* attD2= (const float*)d_in[8];
    const float* b2   = (const float*)d_in[9];
    const float* fcw  = (const float*)d_in[10];
    const float* fcb  = (const float*)d_in[11];
    float* out = (float*)d_out;

    int N = in_sizes[0];          // x is [N,1]
    int E = in_sizes[1] / 2;      // edge_index is [2,E]
    int ET = E + N;               // with self-loops
    int NB = (N + BNODES - 1) / BNODES;   // 128-node coarse buckets (<= NBMAX)
    // padded bucket capacity: mean + 1024 (>>20 sigma for Binomial), 4-aligned
    unsigned cap = (unsigned)((ET + NB - 1) / NB + 1024);
    cap = (cap + 3u) & ~3u;
    size_t padded = (size_t)NB * cap;

    const int* srcI = ei;
    const int* dstI = ei + E;

    float* ws = (float*)d_ws;
    size_t off = 0;
    float*    SD           = ws + off; off += 16;
    unsigned* bucketCursor = (unsigned*)(ws + off); off += NBMAX;
    unsigned* offsets      = (unsigned*)(ws + off); off += (size_t)N + 16;
    int*      pk           = (int*)(ws + off); off += padded;
    int*      sortedSrc    = (int*)(ws + off); off += padded;
    float*    aS2          = ws + off; off += (size_t)N * 8;
    float*    aD2          = ws + off; off += (size_t)N * 8;
    __half*   h2h          = (__half*)(ws + off); off += (size_t)N * 32;  // N*64 halves

    k_prep<<<1, 1024, 0, stream>>>(W1, as1, ad1, SD, bucketCursor, NB, cap);

    int chunk = (ET + NCHUNK - 1) / NCHUNK;
    k_bscatter<<<NCHUNK, TPB, 0, stream>>>(srcI, dstI, E, N, NB, chunk, bucketCursor, pk);
    k_mega    <<<NB, BSZ, 0, stream>>>(pk, bucketCursor, cap, x, SD, W1, b1, W2, attS2, attD2,
                                       N, offsets, sortedSrc, h2h, aS2, aD2);
    k_agg     <<<(N + 3) / 4, TPB, 0, stream>>>(offsets, sortedSrc, aS2, aD2, h2h,
                                                b2, fcw, fcb, out, N);
}